// Round 1
// baseline (6467.775 us; speedup 1.0000x reference)
//
#include <hip/hip_runtime.h>

#define NN   4096
#define BLK  1024
#define BIGF 1e8f
#define GF   0.01f
#define INVG 100.0f

__global__ __launch_bounds__(BLK) void dilate_sdtw(const float* __restrict__ pred,
                                                   const float* __restrict__ target,
                                                   float* __restrict__ out) {
    __shared__ float t_s[NN];
    __shared__ float p_s[NN];
    __shared__ float bufA[NN];
    __shared__ float bufB[NN];
    __shared__ float bufC[NN];

    const int tid = threadIdx.x;

    // Stage sequences; init all diagonal buffers to +inf stand-in.
    for (int i = tid; i < NN; i += BLK) {
        t_s[i]  = target[i];
        p_s[i]  = pred[i];
        bufA[i] = BIGF;
        bufB[i] = BIGF;
        bufC[i] = BIGF;
    }
    __syncthreads();

    float* r2 = bufA;  // diagonal k-2
    float* r1 = bufB;  // diagonal k-1
    float* rn = bufC;  // diagonal k (being written)

    for (int k = 0; k < 2 * NN - 1; ++k) {
        int ilo = k - (NN - 1); if (ilo < 0) ilo = 0;
        int ihi = (k < NN - 1) ? k : (NN - 1);

        for (int i = ilo + tid; i <= ihi; i += BLK) {
            const int j = k - i;
            float diff = t_s[i] - p_s[j];
            float d = diff * diff;

            // R[i-1,j-1]; virtual origin R[-1,-1]=0 only at (0,0).
            float a = (i >= 1 && j >= 1) ? r2[i - 1] : ((k == 0) ? 0.0f : BIGF);
            // R[i-1,j]
            float b = (i >= 1) ? r1[i - 1] : BIGF;
            // R[i,j-1]
            float c = (j >= 1) ? r1[i] : BIGF;

            float m = fminf(a, fminf(b, c));
            // softmin_gamma: m - g*log(sum exp(-(v-m)/g)); min term contributes exactly 1.
            float s = __expf((m - a) * INVG) + __expf((m - b) * INVG) + __expf((m - c) * INVG);
            rn[i] = d + m - GF * __logf(s);
        }
        __syncthreads();

        float* tmp = r2; r2 = r1; r1 = rn; rn = tmp;
    }

    // After the final swap, r1 points at diagonal 2N-2.
    if (tid == 0) out[0] = r1[NN - 1];
}

extern "C" void kernel_launch(void* const* d_in, const int* in_sizes, int n_in,
                              void* d_out, int out_size, void* d_ws, size_t ws_size,
                              hipStream_t stream) {
    const float* pred   = (const float*)d_in[0];
    const float* target = (const float*)d_in[1];
    float* out = (float*)d_out;
    dilate_sdtw<<<dim3(1), dim3(BLK), 0, stream>>>(pred, target, out);
}

// Round 2
// 2040.774 us; speedup vs baseline: 3.1693x; 3.1693x over previous
//
#include <hip/hip_runtime.h>

#define NN     4096
#define BIGF   1e8f
#define GF     0.01f
// softmin via exp2/log2: exp(-(v-m)/g) = exp2((m-v)*K2), g*ln(sum) = GL*log2(sum)
#define K2     144.269504088896340736f   // (1/GAMMA) * log2(e)
#define GL     0.00693147180559945309f   // GAMMA * ln(2)

#define NBLK   64      // row stripes, 64 rows each, one wave per block
#define SCHUNK 32      // columns per flag/boundary chunk
#define NCI    130     // chunk-iterations: steps s = 0 .. 4159 (= NN-1+63, +1 pad)

// ---------------- fallback: single-block diagonal kernel (round-1, verified) ----------------
__global__ __launch_bounds__(1024) void dilate_sdtw(const float* __restrict__ pred,
                                                    const float* __restrict__ target,
                                                    float* __restrict__ out) {
    __shared__ float t_s[NN];
    __shared__ float p_s[NN];
    __shared__ float bufA[NN];
    __shared__ float bufB[NN];
    __shared__ float bufC[NN];
    const int tid = threadIdx.x;
    for (int i = tid; i < NN; i += 1024) {
        t_s[i] = target[i]; p_s[i] = pred[i];
        bufA[i] = BIGF; bufB[i] = BIGF; bufC[i] = BIGF;
    }
    __syncthreads();
    float* r2 = bufA; float* r1 = bufB; float* rn = bufC;
    for (int k = 0; k < 2 * NN - 1; ++k) {
        int ilo = k - (NN - 1); if (ilo < 0) ilo = 0;
        int ihi = (k < NN - 1) ? k : (NN - 1);
        for (int i = ilo + tid; i <= ihi; i += 1024) {
            const int j = k - i;
            float diff = t_s[i] - p_s[j];
            float d = diff * diff;
            float a = (i >= 1 && j >= 1) ? r2[i - 1] : ((k == 0) ? 0.0f : BIGF);
            float b = (i >= 1) ? r1[i - 1] : BIGF;
            float c = (j >= 1) ? r1[i] : BIGF;
            float m = fminf(a, fminf(b, c));
            float s = __expf((m - a) * 100.0f) + __expf((m - b) * 100.0f) + __expf((m - c) * 100.0f);
            rn[i] = d + m - GF * __logf(s);
        }
        __syncthreads();
        float* tmp = r2; r2 = r1; r1 = rn; rn = tmp;
    }
    if (tid == 0) out[0] = r1[NN - 1];
}

// ---------------- pipelined lane-systolic kernel ----------------

__device__ __forceinline__ float softmin3(float a, float b, float c) {
    float m = fminf(a, fminf(b, c));
    float e = exp2f((m - a) * K2) + exp2f((m - b) * K2) + exp2f((m - c) * K2);
    return m - GL * log2f(e);
}

template<bool TOP, bool BOT, bool EDGE>
__device__ __forceinline__ void run_chunk(
    int cs, int lane,
    float& v1, float& v2, float& ubp, float upchunk,
    float t_r, float* pb, int& j,
    const float* p_s, float* bnd_my, float* outp)
{
#pragma unroll 8
    for (int u = 0; u < SCHUNK; ++u) {
        const int s = cs + u;
        float u1 = __shfl_up(v1, 1);   // lane l-1's value @ step s-1 -> R[r-1][j]
        float u2 = __shfl_up(v2, 1);   // lane l-1's value @ step s-2 -> R[r-1][j-1]
        float a, bb;
        if (TOP) {
            float a0 = (s == 0) ? 0.0f : BIGF;   // virtual origin R[-1][-1]=0 at (0,0)
            a  = (lane == 0) ? a0   : u2;
            bb = (lane == 0) ? BIGF : u1;
        } else {
            float ub = __shfl(upchunk, u & 31);  // broadcast up[s] (consumed by lane 0)
            a  = (lane == 0) ? ubp : u2;         // up[j-1]
            bb = (lane == 0) ? ub  : u1;         // up[j]
            ubp = ub;
        }
        float cc = v1;                            // R[r][j-1] (init BIG covers j==0)
        float pj = pb[u & 3];
        float diff = t_r - pj;
        float val = diff * diff + softmin3(a, bb, cc);
        if (EDGE) {
            bool valid = (j >= 0) && (j < NN);
            val = valid ? val : BIGF;
        }
        if (!BOT) {
            if (lane == 63 && (!EDGE || ((unsigned)j < (unsigned)NN))) bnd_my[j] = val;
        } else {
            if (s == NN - 1 + 63 && lane == 63) outp[0] = val;
        }
        v2 = v1; v1 = val;
        // prefetch p for step s+4 (consumed valid only when its j is in range)
        int jn = j + 4;
        jn = jn < 0 ? 0 : jn;
        jn = jn > NN - 1 ? NN - 1 : jn;
        pb[u & 3] = p_s[jn];
        ++j;
    }
}

template<bool TOP, bool BOT>
__device__ void run_stripe(int b, int lane, const float* __restrict__ target,
                           const float* p_s, float* bnd, int* flags, float* outp)
{
    float t_r = target[b * 64 + lane];
    float* bnd_my = bnd + (size_t)b * NN;
    const float* bnd_up = bnd + (size_t)(b - 1) * NN;
    int* flag_my = flags + b;
    int* flag_up = flags + (b - 1);

    float v1 = BIGF, v2 = BIGF, ubp = BIGF;
    float pb[4];
    int j = -lane;
#pragma unroll
    for (int d = 0; d < 4; ++d) {
        int jn = d - lane;
        jn = jn < 0 ? 0 : jn;
        pb[d] = p_s[jn];
    }

    float upcur = BIGF, upnext = BIGF;
    bool have = false;
    int seen = 0;

    for (int ci = 0; ci < NCI; ++ci) {
        const int cs = ci * SCHUNK;
        if (!TOP && cs < NN) {
            const int need = ci + 1;   // flag = count of complete 32-col bottom chunks
            if (seen < need) {
                seen = __hip_atomic_load(flag_up, __ATOMIC_ACQUIRE, __HIP_MEMORY_SCOPE_AGENT);
                while (seen < need) {
                    __builtin_amdgcn_s_sleep(1);
                    seen = __hip_atomic_load(flag_up, __ATOMIC_ACQUIRE, __HIP_MEMORY_SCOPE_AGENT);
                }
            }
            upcur = have ? upnext : bnd_up[cs + (lane & 31)];
            have = false;
            if (cs + SCHUNK < NN && seen >= need + 1) {   // opportunistic next-chunk prefetch
                upnext = bnd_up[cs + SCHUNK + (lane & 31)];
                have = true;
            }
        }
        const bool edge = (ci < 2) || (ci >= 128);
        if (edge) run_chunk<TOP, BOT, true >(cs, lane, v1, v2, ubp, upcur, t_r, pb, j, p_s, bnd_my, outp);
        else      run_chunk<TOP, BOT, false>(cs, lane, v1, v2, ubp, upcur, t_r, pb, j, p_s, bnd_my, outp);
        if (!BOT) {
            const int done = ci - 1;   // chunks 0..ci-2 fully written (lane63 lags by 63 steps)
            if (done >= 1 && lane == 0) {
                __hip_atomic_store(flag_my, done, __ATOMIC_RELEASE, __HIP_MEMORY_SCOPE_AGENT);
            }
        }
    }
}

__global__ __launch_bounds__(64) void sdtw_pipe(const float* __restrict__ pred,
                                                const float* __restrict__ target,
                                                float* __restrict__ out,
                                                float* __restrict__ bnd,
                                                int* __restrict__ flags)
{
    __shared__ float p_s[NN];
    const int lane = threadIdx.x;
    const int b = blockIdx.x;
    for (int i = lane; i < NN; i += 64) p_s[i] = pred[i];
    __syncthreads();
    if (b == 0)                run_stripe<true , false>(b, lane, target, p_s, bnd, flags, out);
    else if (b == NBLK - 1)    run_stripe<false, true >(b, lane, target, p_s, bnd, flags, out);
    else                       run_stripe<false, false>(b, lane, target, p_s, bnd, flags, out);
}

extern "C" void kernel_launch(void* const* d_in, const int* in_sizes, int n_in,
                              void* d_out, int out_size, void* d_ws, size_t ws_size,
                              hipStream_t stream) {
    const float* pred   = (const float*)d_in[0];
    const float* target = (const float*)d_in[1];
    float* out = (float*)d_out;

    const size_t need = 512 + (size_t)NBLK * NN * sizeof(float);
    if (ws_size >= need) {
        int*   flags = (int*)d_ws;
        float* bnd   = (float*)((char*)d_ws + 512);
        hipMemsetAsync(d_ws, 0, 512, stream);   // reset flags every call (graph-capture safe)
        sdtw_pipe<<<dim3(NBLK), dim3(64), 0, stream>>>(pred, target, out, bnd, flags);
    } else {
        dilate_sdtw<<<dim3(1), dim3(1024), 0, stream>>>(pred, target, out);
    }
}

// Round 3
// 1428.195 us; speedup vs baseline: 4.5286x; 1.4289x over previous
//
#include <hip/hip_runtime.h>

#define NN    4096
#define BIGF  1e8f
#define K2f   144.269504088896340736f   // (1/GAMMA) * log2(e)
#define GLf   0.00693147180559945309f   // GAMMA * ln(2)
#define NBLK  32
#define SCH   32
#define NCI   132      // ceil((NN + SKEW)/SCH) = ceil(4222/32)
#define SKEW  126      // (64-1) lanes * 2-column stagger

// ---------------- fallback: single-block diagonal kernel (verified r1) ----------------
__global__ __launch_bounds__(1024) void dilate_sdtw(const float* __restrict__ pred,
                                                    const float* __restrict__ target,
                                                    float* __restrict__ out) {
    __shared__ float t_s[NN];
    __shared__ float p_s[NN];
    __shared__ float bufA[NN];
    __shared__ float bufB[NN];
    __shared__ float bufC[NN];
    const int tid = threadIdx.x;
    for (int i = tid; i < NN; i += 1024) {
        t_s[i] = target[i]; p_s[i] = pred[i];
        bufA[i] = BIGF; bufB[i] = BIGF; bufC[i] = BIGF;
    }
    __syncthreads();
    float* r2 = bufA; float* r1 = bufB; float* rn = bufC;
    for (int k = 0; k < 2 * NN - 1; ++k) {
        int ilo = k - (NN - 1); if (ilo < 0) ilo = 0;
        int ihi = (k < NN - 1) ? k : (NN - 1);
        for (int i = ilo + tid; i <= ihi; i += 1024) {
            const int j = k - i;
            float diff = t_s[i] - p_s[j];
            float d = diff * diff;
            float a = (i >= 1 && j >= 1) ? r2[i - 1] : ((k == 0) ? 0.0f : BIGF);
            float b = (i >= 1) ? r1[i - 1] : BIGF;
            float c = (j >= 1) ? r1[i] : BIGF;
            float m = fminf(a, fminf(b, c));
            float s = __expf((m - a) * 100.0f) + __expf((m - b) * 100.0f) + __expf((m - c) * 100.0f);
            rn[i] = d + m - 0.01f * __logf(s);
        }
        __syncthreads();
        float* tmp = r2; r2 = r1; r1 = rn; rn = tmp;
    }
    if (tid == 0) out[0] = r1[NN - 1];
}

// ---------------- R=2 lane-systolic, stagger-2, register-chunked ----------------

__device__ __forceinline__ float softmin3(float a, float b, float c) {
    float m = fminf(a, fminf(b, c));
    float e = __builtin_amdgcn_exp2f((m - a) * K2f)
            + __builtin_amdgcn_exp2f((m - b) * K2f)
            + __builtin_amdgcn_exp2f((m - c) * K2f);
    return m - GLf * __builtin_amdgcn_logf(e);   // logf builtin = log2
}

__device__ __forceinline__ int load_flag(const int* f) {
    return __hip_atomic_load(f, __ATOMIC_ACQUIRE, __HIP_MEMORY_SCOPE_AGENT);
}

// p for one chunk: 32 consecutive columns starting at `base` (clamped), as 16 float2.
__device__ __forceinline__ void pload(const float* p_s, int base, float2* dst) {
#pragma unroll
    for (int q = 0; q < 16; ++q) {
        int idx = base + 2 * q;                 // base is even -> idx even -> 8B aligned
        idx = idx < 0 ? 0 : (idx > NN - 2 ? NN - 2 : idx);
        dst[q] = *(const float2*)(p_s + idx);
    }
}

// upstream boundary chunk: 32 floats, loaded uniformly by all lanes (broadcast).
__device__ __forceinline__ void upload(const float* src, float* dst) {
#pragma unroll
    for (int q = 0; q < 8; ++q)
        *(float4*)(dst + 4 * q) = *(const float4*)(src + 4 * q);
}

template<bool TOP, bool BOT, bool EDGE>
__device__ __forceinline__ void chunk32(
    int cs, int lane, float t0, float t1,
    float& v0, float& v1, float& u1, float& u2, float up_last,
    const float* upc, const float2* pc,
    float* __restrict__ bnd_my, float* __restrict__ outp)
{
#pragma unroll
    for (int u = 0; u < SCH; ++u) {
        const int s = cs + u;
        const int j = s - 2 * lane;
        // shuffle for NEXT step's u1: lane l-1's v1 @ s-1 (v1 not yet updated)
        float nxt = __shfl_up(v1, 1);
        float pj = (u & 1) ? pc[u >> 1].y : pc[u >> 1].x;
        float a, b;
        if (TOP) {
            a = (lane == 0) ? ((s == 0) ? 0.0f : BIGF) : u2;
            b = (lane == 0) ? BIGF : u1;
        } else {
            float upj  = upc[u];
            float upjm = (u == 0) ? up_last : upc[u - 1];
            a = (lane == 0) ? upjm : u2;
            b = (lane == 0) ? upj  : u1;
        }
        float d0 = t0 - pj;
        float val0 = d0 * d0 + softmin3(a, b, v0);      // row 2l, col j
        float d1 = t1 - pj;
        float val1 = d1 * d1 + softmin3(v0, val0, v1);  // row 2l+1, col j
        if (EDGE) {
            bool valid = (unsigned)j < (unsigned)NN;
            val0 = valid ? val0 : BIGF;
            val1 = valid ? val1 : BIGF;
        }
        if (!BOT) {
            if (lane == 63 && (!EDGE || (unsigned)j < (unsigned)NN)) bnd_my[j] = val1;
        } else if (EDGE) {
            if (lane == 63 && s == NN - 1 + SKEW) outp[0] = val1;
        }
        v0 = val0; v1 = val1;
        u2 = u1; u1 = nxt;
    }
}

template<bool TOP, bool BOT>
__device__ __forceinline__ void chunk_iter(
    int ci, int lane, float t0, float t1,
    float& v0, float& v1, float& u1, float& u2, float& up_last,
    float* upX, float* upY, float2* pX, float2* pY,
    bool& haveX, bool& haveY, int& seen,
    const float* p_s, const float* __restrict__ bnd_up, float* __restrict__ bnd_my,
    int* flag_my, const int* flag_up, float* __restrict__ outp)
{
    const int cs = ci * SCH;
    if (!TOP && cs < NN) {
        if (!haveX) {
            const int need = ci + 1;
            if (seen < need) {
                seen = load_flag(flag_up);
                while (seen < need) { __builtin_amdgcn_s_sleep(1); seen = load_flag(flag_up); }
            }
            upload(bnd_up + cs, upX);
        }
        if (cs + SCH < NN) {           // opportunistic prefetch of chunk ci+1
            if (seen < ci + 2) seen = load_flag(flag_up);
            if (seen >= ci + 2) { upload(bnd_up + cs + SCH, upY); haveY = true; }
            else haveY = false;
        }
    }
    if (ci + 1 < NCI) pload(p_s, cs + SCH - 2 * lane, pY);

    const bool edge = (ci < 4) || (ci >= 128);
    if (edge) chunk32<TOP, BOT, true >(cs, lane, t0, t1, v0, v1, u1, u2, up_last, upX, pX, bnd_my, outp);
    else      chunk32<TOP, BOT, false>(cs, lane, t0, t1, v0, v1, u1, u2, up_last, upX, pX, bnd_my, outp);

    up_last = upX[SCH - 1];
    haveX = false;
    if (!BOT) {
        const int done = ci - 3;       // lane63 lags 126 cols: chunks 0..ci-4 complete
        if (done >= 1) __hip_atomic_store(flag_my, done, __ATOMIC_RELEASE, __HIP_MEMORY_SCOPE_AGENT);
    }
}

template<bool TOP, bool BOT>
__device__ void stripe(int b, int lane, const float* __restrict__ target,
                       const float* p_s, float* bnd, int* flags, float* outp)
{
    const float t0 = target[256 * b + 2 * lane];
    const float t1 = target[256 * b + 2 * lane + 1];
    float* bnd_my = bnd + (size_t)b * NN;
    const float* bnd_up = bnd + (size_t)(b - 1) * NN;
    int* flag_my = flags + b;
    const int* flag_up = flags + (b - 1);

    float v0 = BIGF, v1 = BIGF, u1 = BIGF, u2 = BIGF, up_last = BIGF;
    float upA[SCH], upB[SCH];
    float2 pA[16], pB[16];
    bool haveA = false, haveB = false;
    int seen = 0;

    pload(p_s, -2 * lane, pA);

    for (int cp = 0; cp < NCI / 2; ++cp) {
        chunk_iter<TOP, BOT>(2 * cp,     lane, t0, t1, v0, v1, u1, u2, up_last,
                             upA, upB, pA, pB, haveA, haveB, seen,
                             p_s, bnd_up, bnd_my, flag_my, flag_up, outp);
        chunk_iter<TOP, BOT>(2 * cp + 1, lane, t0, t1, v0, v1, u1, u2, up_last,
                             upB, upA, pB, pA, haveB, haveA, seen,
                             p_s, bnd_up, bnd_my, flag_my, flag_up, outp);
    }
}

__global__ __launch_bounds__(64) void sdtw_pipe2(const float* __restrict__ pred,
                                                 const float* __restrict__ target,
                                                 float* __restrict__ out,
                                                 float* __restrict__ bnd,
                                                 int* __restrict__ flags)
{
    __shared__ float p_s[NN];
    const int lane = threadIdx.x;
    const int b = blockIdx.x;
    for (int i = lane; i < NN; i += 64) p_s[i] = pred[i];
    __syncthreads();
    if (b == 0)                stripe<true , false>(b, lane, target, p_s, bnd, flags, out);
    else if (b == NBLK - 1)    stripe<false, true >(b, lane, target, p_s, bnd, flags, out);
    else                       stripe<false, false>(b, lane, target, p_s, bnd, flags, out);
}

extern "C" void kernel_launch(void* const* d_in, const int* in_sizes, int n_in,
                              void* d_out, int out_size, void* d_ws, size_t ws_size,
                              hipStream_t stream) {
    const float* pred   = (const float*)d_in[0];
    const float* target = (const float*)d_in[1];
    float* out = (float*)d_out;

    const size_t need = 512 + (size_t)NBLK * NN * sizeof(float);
    if (ws_size >= need) {
        int*   flags = (int*)d_ws;
        float* bnd   = (float*)((char*)d_ws + 512);
        hipMemsetAsync(d_ws, 0, 512, stream);   // zero flags each call (graph-capture safe)
        sdtw_pipe2<<<dim3(NBLK), dim3(64), 0, stream>>>(pred, target, out, bnd, flags);
    } else {
        dilate_sdtw<<<dim3(1), dim3(1024), 0, stream>>>(pred, target, out);
    }
}

// Round 4
// 1210.337 us; speedup vs baseline: 5.3438x; 1.1800x over previous
//
#include <hip/hip_runtime.h>

#define NN    4096
#define BIGF  1e8f
// Scaled domain: R' = R * K2, K2 = (1/GAMMA)*log2(e). Then
// softmin'(a,b,c) = m - log2(exp2(m-a)+exp2(m-b)+exp2(m-c))  (no multiplies),
// d' = (sqrt(K2)*t - sqrt(K2)*p)^2, final loss = R'[N-1][N-1] / K2.
#define SQK2f 12.0112245225638540f    // sqrt(144.269504088896340736)
#define BIGK  1.4426950408889634e10f  // 1e8 * K2
#define IK2f  0.00693147180559945309f // 1/K2 = GAMMA*ln2
#define NBLK  32
#define SCH   32
#define NCI   132      // ceil((NN + SKEW + 1)/SCH)
#define SKEW  126      // (64-1) lanes * 2-column stagger

// ---------------- fallback: single-block diagonal kernel (verified r1) ----------------
__global__ __launch_bounds__(1024) void dilate_sdtw(const float* __restrict__ pred,
                                                    const float* __restrict__ target,
                                                    float* __restrict__ out) {
    __shared__ float t_s[NN];
    __shared__ float p_s[NN];
    __shared__ float bufA[NN];
    __shared__ float bufB[NN];
    __shared__ float bufC[NN];
    const int tid = threadIdx.x;
    for (int i = tid; i < NN; i += 1024) {
        t_s[i] = target[i]; p_s[i] = pred[i];
        bufA[i] = BIGF; bufB[i] = BIGF; bufC[i] = BIGF;
    }
    __syncthreads();
    float* r2 = bufA; float* r1 = bufB; float* rn = bufC;
    for (int k = 0; k < 2 * NN - 1; ++k) {
        int ilo = k - (NN - 1); if (ilo < 0) ilo = 0;
        int ihi = (k < NN - 1) ? k : (NN - 1);
        for (int i = ilo + tid; i <= ihi; i += 1024) {
            const int j = k - i;
            float diff = t_s[i] - p_s[j];
            float d = diff * diff;
            float a = (i >= 1 && j >= 1) ? r2[i - 1] : ((k == 0) ? 0.0f : BIGF);
            float b = (i >= 1) ? r1[i - 1] : BIGF;
            float c = (j >= 1) ? r1[i] : BIGF;
            float m = fminf(a, fminf(b, c));
            float s = __expf((m - a) * 100.0f) + __expf((m - b) * 100.0f) + __expf((m - c) * 100.0f);
            rn[i] = d + m - 0.01f * __logf(s);
        }
        __syncthreads();
        float* tmp = r2; r2 = r1; r1 = rn; rn = tmp;
    }
    if (tid == 0) out[0] = r1[NN - 1];
}

// ---------------- R=2 lane-systolic, stagger-2, K2-scaled, register-chunked ----------------

__device__ __forceinline__ float softmin3s(float a, float b, float c) {
    // scaled domain: no multiplies
    float m = fminf(a, fminf(b, c));
    float e = __builtin_amdgcn_exp2f(m - a)
            + __builtin_amdgcn_exp2f(m - b)
            + __builtin_amdgcn_exp2f(m - c);
    return m - __builtin_amdgcn_logf(e);   // logf builtin = log2
}

__device__ __forceinline__ int load_flag_rlx(const int* f) {
    return __hip_atomic_load(f, __ATOMIC_RELAXED, __HIP_MEMORY_SCOPE_AGENT);
}

// p for one chunk: 32 consecutive columns starting at even `base` (clamped), 16x float2.
__device__ __forceinline__ void pload(const float* p_s, int base, float2* dst) {
#pragma unroll
    for (int q = 0; q < 16; ++q) {
        int idx = base + 2 * q;
        idx = idx < 0 ? 0 : (idx > NN - 2 ? NN - 2 : idx);
        dst[q] = *(const float2*)(p_s + idx);
    }
}

// upstream boundary chunk: 32 floats, loaded uniformly by all lanes (broadcast).
__device__ __forceinline__ void upload(const float* src, float* dst) {
#pragma unroll
    for (int q = 0; q < 8; ++q)
        *(float4*)(dst + 4 * q) = *(const float4*)(src + 4 * q);
}

template<bool TOP, bool BOT, bool EDGE>
__device__ __forceinline__ void chunk32(
    int cs, int lane, bool l0, float t0, float t1,
    float& v0, float& v1, float& u1, float& u2, float up_last, float4& acc,
    const float* upc, const float2* pc,
    float* __restrict__ bnd_my, float* __restrict__ outp)
{
#pragma unroll
    for (int u = 0; u < SCH; ++u) {
        const int s = cs + u;
        const int j = s - 2 * lane;
        // shuffle for NEXT step's u1: lane l-1's v1 @ s-1 (v1 not yet updated)
        float nxt = __shfl_up(v1, 1);
        float pj = (u & 1) ? pc[u >> 1].y : pc[u >> 1].x;
        float a, b;
        if (TOP) {
            a = l0 ? ((s == 0) ? 0.0f : BIGK) : u2;
            b = l0 ? BIGK : u1;
        } else {
            float upj  = upc[u];
            float upjm = (u == 0) ? up_last : upc[u - 1];
            a = l0 ? upjm : u2;
            b = l0 ? upj  : u1;
        }
        float d0 = t0 - pj;
        float val0 = fmaf(d0, d0, softmin3s(a, b, v0));      // row 2l, col j
        float d1 = t1 - pj;
        float val1 = fmaf(d1, d1, softmin3s(v0, val0, v1));  // row 2l+1, col j
        if (EDGE) {
            bool valid = (unsigned)j < (unsigned)NN;
            val0 = valid ? val0 : BIGK;
            val1 = valid ? val1 : BIGK;
        }
        if (!BOT) {
            // collect 4 consecutive columns (j&3 == (u+2)&3), store float4 at j&3==3
            switch (u & 3) {
                case 2: acc.x = val1; break;
                case 3: acc.y = val1; break;
                case 0: acc.z = val1; break;
                case 1: acc.w = val1; break;
            }
            if ((u & 3) == 1) {
                if (lane == 63 && (unsigned)(j - 3) <= (unsigned)(NN - 4))
                    *(float4*)(bnd_my + (j - 3)) = acc;
            }
        } else if (EDGE) {
            if (lane == 63 && s == NN - 1 + SKEW) outp[0] = val1 * IK2f;
        }
        v0 = val0; v1 = val1;
        u2 = u1; u1 = nxt;
    }
}

template<bool TOP, bool BOT>
__device__ __forceinline__ void chunk_iter(
    int ci, int lane, bool l0, float t0, float t1,
    float& v0, float& v1, float& u1, float& u2, float& up_last, float4& acc,
    float* upX, float* upY, float2* pX, float2* pY,
    bool& haveX, bool& haveY, int& seen,
    const float* p_s, const float* __restrict__ bnd_up, float* __restrict__ bnd_my,
    int* flag_my, const int* flag_up, float* __restrict__ outp)
{
    const int cs = ci * SCH;
    if (!TOP && cs < NN) {
        bool doY = false;
        if (!haveX) {
            const int need = ci + 1;
            if (seen < need) {
                seen = load_flag_rlx(flag_up);
                while (seen < need) { __builtin_amdgcn_s_sleep(1); seen = load_flag_rlx(flag_up); }
            }
        }
        if (cs + SCH < NN) {
            if (seen < ci + 2) seen = load_flag_rlx(flag_up);
            doY = (seen >= ci + 2);
        }
        if (!haveX || doY) __builtin_amdgcn_fence(__ATOMIC_ACQUIRE, "agent");
        if (!haveX) upload(bnd_up + cs, upX);
        if (doY)    upload(bnd_up + cs + SCH, upY);
        haveY = doY;
    }
    if (ci + 1 < NCI) pload(p_s, cs + SCH - 2 * lane, pY);

    const bool edge = (ci < 4) || (ci >= 128);
    if (edge) chunk32<TOP, BOT, true >(cs, lane, l0, t0, t1, v0, v1, u1, u2, up_last, acc, upX, pX, bnd_my, outp);
    else      chunk32<TOP, BOT, false>(cs, lane, l0, t0, t1, v0, v1, u1, u2, up_last, acc, upX, pX, bnd_my, outp);

    up_last = upX[SCH - 1];
    haveX = false;
    if (!BOT) {
        const int done = ci - 3;       // lane63 lags 126 cols; float4 groups land exactly at chunk ci-4 end
        if (done >= 1 && lane == 63)
            __hip_atomic_store(flag_my, done, __ATOMIC_RELEASE, __HIP_MEMORY_SCOPE_AGENT);
    }
}

template<bool TOP, bool BOT>
__device__ void stripe(int b, int lane, const float* __restrict__ target,
                       const float* p_s, float* bnd, int* flags, float* outp)
{
    const float t0 = target[256 * b + 2 * lane] * SQK2f;
    const float t1 = target[256 * b + 2 * lane + 1] * SQK2f;
    float* bnd_my = bnd + (size_t)b * NN;
    const float* bnd_up = bnd + (size_t)(b - 1) * NN;
    int* flag_my = flags + b;
    const int* flag_up = flags + (b - 1);
    const bool l0 = (lane == 0);

    float v0 = BIGK, v1 = BIGK, u1 = BIGK, u2 = BIGK, up_last = BIGK;
    float4 acc = {BIGK, BIGK, BIGK, BIGK};
    float upA[SCH], upB[SCH];
    float2 pA[16], pB[16];
    bool haveA = false, haveB = false;
    int seen = 0;

    pload(p_s, -2 * lane, pA);

    for (int cp = 0; cp < NCI / 2; ++cp) {
        chunk_iter<TOP, BOT>(2 * cp,     lane, l0, t0, t1, v0, v1, u1, u2, up_last, acc,
                             upA, upB, pA, pB, haveA, haveB, seen,
                             p_s, bnd_up, bnd_my, flag_my, flag_up, outp);
        chunk_iter<TOP, BOT>(2 * cp + 1, lane, l0, t0, t1, v0, v1, u1, u2, up_last, acc,
                             upB, upA, pB, pA, haveB, haveA, seen,
                             p_s, bnd_up, bnd_my, flag_my, flag_up, outp);
    }
}

__global__ __launch_bounds__(64) void sdtw_pipe3(const float* __restrict__ pred,
                                                 const float* __restrict__ target,
                                                 float* __restrict__ out,
                                                 float* __restrict__ bnd,
                                                 int* __restrict__ flags)
{
    __shared__ float p_s[NN];
    const int lane = threadIdx.x;
    // Group 4 consecutive stripes per XCD (dispatch heuristic: bid%8 -> XCD).
    const int bid = blockIdx.x;
    const int b = (bid & 7) * 4 + (bid >> 3);
    for (int i = lane; i < NN; i += 64) p_s[i] = pred[i] * SQK2f;
    __syncthreads();
    if (b == 0)                stripe<true , false>(b, lane, target, p_s, bnd, flags, out);
    else if (b == NBLK - 1)    stripe<false, true >(b, lane, target, p_s, bnd, flags, out);
    else                       stripe<false, false>(b, lane, target, p_s, bnd, flags, out);
}

extern "C" void kernel_launch(void* const* d_in, const int* in_sizes, int n_in,
                              void* d_out, int out_size, void* d_ws, size_t ws_size,
                              hipStream_t stream) {
    const float* pred   = (const float*)d_in[0];
    const float* target = (const float*)d_in[1];
    float* out = (float*)d_out;

    const size_t need = 512 + (size_t)NBLK * NN * sizeof(float);
    if (ws_size >= need) {
        int*   flags = (int*)d_ws;
        float* bnd   = (float*)((char*)d_ws + 512);
        hipMemsetAsync(d_ws, 0, 512, stream);   // zero flags each call (graph-capture safe)
        sdtw_pipe3<<<dim3(NBLK), dim3(64), 0, stream>>>(pred, target, out, bnd, flags);
    } else {
        dilate_sdtw<<<dim3(1), dim3(1024), 0, stream>>>(pred, target, out);
    }
}

// Round 5
// 1112.154 us; speedup vs baseline: 5.8155x; 1.0883x over previous
//
#include <hip/hip_runtime.h>

#define NN    4096
#define BIGF  1e8f
// Scaled domain: R' = R * K2, K2 = (1/GAMMA)*log2(e).
// softmin'(a,b,c) = m - log2(exp2(m-a)+exp2(m-b)+exp2(m-c)); loss = R'/K2.
#define SQK2f 12.0112245225638540f    // sqrt(144.269504088896340736)
#define BIGK  1.4426950408889634e10f  // 1e8 * K2
#define IK2f  0.00693147180559945309f // 1/K2 = GAMMA*ln2
#define NBLK  32
#define SCH   32
#define NCI   132      // ceil((NN + SKEW + 1)/SCH)
#define SKEW  126      // (64-1) lanes * 2-column stagger
#define SENTU 0xFFFFFFFFu   // NaN sentinel: DP values are never NaN

// ---------------- fallback: single-block diagonal kernel (verified r1) ----------------
__global__ __launch_bounds__(1024) void dilate_sdtw(const float* __restrict__ pred,
                                                    const float* __restrict__ target,
                                                    float* __restrict__ out) {
    __shared__ float t_s[NN];
    __shared__ float p_s[NN];
    __shared__ float bufA[NN];
    __shared__ float bufB[NN];
    __shared__ float bufC[NN];
    const int tid = threadIdx.x;
    for (int i = tid; i < NN; i += 1024) {
        t_s[i] = target[i]; p_s[i] = pred[i];
        bufA[i] = BIGF; bufB[i] = BIGF; bufC[i] = BIGF;
    }
    __syncthreads();
    float* r2 = bufA; float* r1 = bufB; float* rn = bufC;
    for (int k = 0; k < 2 * NN - 1; ++k) {
        int ilo = k - (NN - 1); if (ilo < 0) ilo = 0;
        int ihi = (k < NN - 1) ? k : (NN - 1);
        for (int i = ilo + tid; i <= ihi; i += 1024) {
            const int j = k - i;
            float diff = t_s[i] - p_s[j];
            float d = diff * diff;
            float a = (i >= 1 && j >= 1) ? r2[i - 1] : ((k == 0) ? 0.0f : BIGF);
            float b = (i >= 1) ? r1[i - 1] : BIGF;
            float c = (j >= 1) ? r1[i] : BIGF;
            float m = fminf(a, fminf(b, c));
            float s = __expf((m - a) * 100.0f) + __expf((m - b) * 100.0f) + __expf((m - c) * 100.0f);
            rn[i] = d + m - 0.01f * __logf(s);
        }
        __syncthreads();
        float* tmp = r2; r2 = r1; r1 = rn; rn = tmp;
    }
    if (tid == 0) out[0] = r1[NN - 1];
}

// ---------------- R=2 lane-systolic, stagger-2, K2-scaled, fence-free sync ----------------

__device__ __forceinline__ float softmin3s(float a, float b, float c) {
    float m = fminf(a, fminf(b, c));
    float e = __builtin_amdgcn_exp2f(m - a)
            + __builtin_amdgcn_exp2f(m - b)
            + __builtin_amdgcn_exp2f(m - c);
    return m - __builtin_amdgcn_logf(e);   // logf builtin = log2
}

// relaxed agent-scope atomics: bypass L1/L2 to the coherence point, no fences.
__device__ __forceinline__ void bput(float* p, float v) {
    __hip_atomic_store((unsigned int*)p, __float_as_uint(v),
                       __ATOMIC_RELAXED, __HIP_MEMORY_SCOPE_AGENT);
}
__device__ __forceinline__ unsigned int bgetu(const float* p) {
    return __hip_atomic_load((const unsigned int*)p,
                             __ATOMIC_RELAXED, __HIP_MEMORY_SCOPE_AGENT);
}

// blocking poll-load of one 32-word boundary chunk (uniform addr across lanes)
__device__ __forceinline__ void upoll(const float* src, float* dst) {
    bool ready;
    do {
        ready = true;
#pragma unroll
        for (int q = 0; q < SCH; ++q) {
            unsigned int u = bgetu(src + q);
            dst[q] = __uint_as_float(u);
            ready &= (u != SENTU);
        }
        if (!ready) __builtin_amdgcn_s_sleep(2);
    } while (!ready);
}
// one-try load; true if complete (prefetch)
__device__ __forceinline__ bool utry(const float* src, float* dst) {
    bool ready = true;
#pragma unroll
    for (int q = 0; q < SCH; ++q) {
        unsigned int u = bgetu(src + q);
        dst[q] = __uint_as_float(u);
        ready &= (u != SENTU);
    }
    return ready;
}

// p for one chunk: 32 consecutive columns starting at even `base` (clamped), 16x float2.
__device__ __forceinline__ void pload(const float* p_s, int base, float2* dst) {
#pragma unroll
    for (int q = 0; q < 16; ++q) {
        int idx = base + 2 * q;
        idx = idx < 0 ? 0 : (idx > NN - 2 ? NN - 2 : idx);
        dst[q] = *(const float2*)(p_s + idx);
    }
}

template<bool TOP, bool BOT, bool EDGE>
__device__ __forceinline__ void chunk32(
    int cs, int lane, bool l0, float t0, float t1,
    float& v0, float& v1, float& u1, float& u2, float up_last, float4& acc,
    const float* upc, const float2* pc,
    float* __restrict__ bnd_my, float* __restrict__ outp)
{
#pragma unroll
    for (int u = 0; u < SCH; ++u) {
        const int s = cs + u;
        const int j = s - 2 * lane;
        // shuffle for NEXT step's u1: lane l-1's v1 @ s-1 (v1 not yet updated)
        float nxt = __shfl_up(v1, 1);
        float pj = (u & 1) ? pc[u >> 1].y : pc[u >> 1].x;
        float a, b;
        if (TOP) {
            a = l0 ? ((s == 0) ? 0.0f : BIGK) : u2;
            b = l0 ? BIGK : u1;
        } else {
            float upj  = upc[u];
            float upjm = (u == 0) ? up_last : upc[u - 1];
            a = l0 ? upjm : u2;
            b = l0 ? upj  : u1;
        }
        float d0 = t0 - pj;
        float val0 = fmaf(d0, d0, softmin3s(a, b, v0));      // row 2l, col j
        float d1 = t1 - pj;
        float val1 = fmaf(d1, d1, softmin3s(v0, val0, v1));  // row 2l+1, col j
        if (EDGE) {
            bool valid = (unsigned)j < (unsigned)NN;
            val0 = valid ? val0 : BIGK;
            val1 = valid ? val1 : BIGK;
        }
        if (!BOT) {
            // collect 4 consecutive columns; publish as 4 relaxed atomic stores
            switch (u & 3) {
                case 2: acc.x = val1; break;
                case 3: acc.y = val1; break;
                case 0: acc.z = val1; break;
                case 1: acc.w = val1; break;
            }
            if ((u & 3) == 1) {
                if (lane == 63 && (unsigned)(j - 3) <= (unsigned)(NN - 4)) {
                    bput(bnd_my + (j - 3), acc.x);
                    bput(bnd_my + (j - 2), acc.y);
                    bput(bnd_my + (j - 1), acc.z);
                    bput(bnd_my + (j - 0), acc.w);
                }
            }
        } else if (EDGE) {
            if (lane == 63 && s == NN - 1 + SKEW) outp[0] = val1 * IK2f;
        }
        v0 = val0; v1 = val1;
        u2 = u1; u1 = nxt;
    }
}

template<bool TOP, bool BOT>
__device__ __forceinline__ void chunk_iter(
    int ci, int lane, bool l0, float t0, float t1,
    float& v0, float& v1, float& u1, float& u2, float& up_last, float4& acc,
    float* upX, float* upY, float2* pX, float2* pY,
    bool& haveX, bool& haveY,
    const float* p_s, const float* __restrict__ bnd_up, float* __restrict__ bnd_my,
    float* __restrict__ outp)
{
    const int cs = ci * SCH;
    if (!TOP && cs < NN) {
        if (!haveX) upoll(bnd_up + cs, upX);            // blocking (steady state: one pass)
        if (cs + SCH < NN) haveY = utry(bnd_up + cs + SCH, upY);   // prefetch next chunk
        else haveY = false;
    }
    if (ci + 1 < NCI) pload(p_s, cs + SCH - 2 * lane, pY);

    const bool edge = (ci < 4) || (ci >= 128);
    if (edge) chunk32<TOP, BOT, true >(cs, lane, l0, t0, t1, v0, v1, u1, u2, up_last, acc, upX, pX, bnd_my, outp);
    else      chunk32<TOP, BOT, false>(cs, lane, l0, t0, t1, v0, v1, u1, u2, up_last, acc, upX, pX, bnd_my, outp);

    up_last = upX[SCH - 1];
    haveX = false;
}

template<bool TOP, bool BOT>
__device__ void stripe(int b, int lane, const float* __restrict__ target,
                       const float* p_s, float* bnd, float* outp)
{
    const float t0 = target[256 * b + 2 * lane] * SQK2f;
    const float t1 = target[256 * b + 2 * lane + 1] * SQK2f;
    float* bnd_my = bnd + (size_t)b * NN;
    const float* bnd_up = bnd + (size_t)(b - 1) * NN;
    const bool l0 = (lane == 0);

    float v0 = BIGK, v1 = BIGK, u1 = BIGK, u2 = BIGK, up_last = BIGK;
    float4 acc = {BIGK, BIGK, BIGK, BIGK};
    float upA[SCH], upB[SCH];
    float2 pA[16], pB[16];
    bool haveA = false, haveB = false;

    pload(p_s, -2 * lane, pA);

    for (int cp = 0; cp < NCI / 2; ++cp) {
        chunk_iter<TOP, BOT>(2 * cp,     lane, l0, t0, t1, v0, v1, u1, u2, up_last, acc,
                             upA, upB, pA, pB, haveA, haveB,
                             p_s, bnd_up, bnd_my, outp);
        chunk_iter<TOP, BOT>(2 * cp + 1, lane, l0, t0, t1, v0, v1, u1, u2, up_last, acc,
                             upB, upA, pB, pA, haveB, haveA,
                             p_s, bnd_up, bnd_my, outp);
    }
}

__global__ __launch_bounds__(64) void sdtw_pipe4(const float* __restrict__ pred,
                                                 const float* __restrict__ target,
                                                 float* __restrict__ out,
                                                 float* __restrict__ bnd)
{
    __shared__ float p_s[NN];
    const int lane = threadIdx.x;
    // Group 4 consecutive stripes per XCD (dispatch heuristic: bid%8 -> XCD).
    const int bid = blockIdx.x;
    const int b = (bid & 7) * 4 + (bid >> 3);
    for (int i = lane; i < NN; i += 64) p_s[i] = pred[i] * SQK2f;
    __syncthreads();
    if (b == 0)                stripe<true , false>(b, lane, target, p_s, bnd, out);
    else if (b == NBLK - 1)    stripe<false, true >(b, lane, target, p_s, bnd, out);
    else                       stripe<false, false>(b, lane, target, p_s, bnd, out);
}

extern "C" void kernel_launch(void* const* d_in, const int* in_sizes, int n_in,
                              void* d_out, int out_size, void* d_ws, size_t ws_size,
                              hipStream_t stream) {
    const float* pred   = (const float*)d_in[0];
    const float* target = (const float*)d_in[1];
    float* out = (float*)d_out;

    const size_t need = (size_t)NBLK * NN * sizeof(float);
    if (ws_size >= need) {
        float* bnd = (float*)d_ws;
        // NaN sentinel fill: value-carried readiness (graph-capture safe)
        hipMemsetAsync(d_ws, 0xFF, need, stream);
        sdtw_pipe4<<<dim3(NBLK), dim3(64), 0, stream>>>(pred, target, out, bnd);
    } else {
        dilate_sdtw<<<dim3(1), dim3(1024), 0, stream>>>(pred, target, out);
    }
}